// Round 1
// 1266.088 us; speedup vs baseline: 6.4848x; 6.4848x over previous
//
#include <hip/hip_runtime.h>

// WindowAttentionLite on MFMA: x(4,256,256,256) fp32, w_qkv(768,256), w_proj(256,256)
// WINDOW=8 -> 64 tokens/window, 8 heads, head_dim=32. One block per window, 8 waves.
// All matmul phases on v_mfma_f32_16x16x32_f16 (K=32 == head_dim). fp32 accum.

#define DIMC 256
#define NH   8
#define HD   32
#define WS   8
#define NTOK 64
#define HRES 256
#define IMG  (HRES * HRES)

typedef _Float16 f16x8 __attribute__((ext_vector_type(8)));
typedef _Float16 f16x4 __attribute__((ext_vector_type(4)));
typedef float    f32x4 __attribute__((ext_vector_type(4)));

#define MFMA(a, b, c) __builtin_amdgcn_mfma_f32_16x16x32_f16((a), (b), (c), 0, 0, 0)

// ---------- prologue: convert weights fp32 -> fp16 into workspace ----------
__global__ __launch_bounds__(256) void cvt_weights(const float* __restrict__ wqkv,
                                                   const float* __restrict__ wproj,
                                                   _Float16* __restrict__ wq,
                                                   _Float16* __restrict__ wp)
{
    int i = blockIdx.x * 256 + threadIdx.x;
    const int NQ = 768 * 256;
    const int NT = NQ + 256 * 256;
    if (i < NQ)      wq[i] = (_Float16)wqkv[i];
    else if (i < NT) wp[i - NQ] = (_Float16)wproj[i - NQ];
}

// A-fragment load: PRE=1 -> fp16 from workspace; PRE=0 -> fp32 direct + convert
template <int PRE>
__device__ __forceinline__ f16x8 ldw(const void* w, int idx)
{
    if constexpr (PRE) {
        return *(const f16x8*)((const _Float16*)w + idx);
    } else {
        const float* p = (const float*)w + idx;
        f16x8 r;
        #pragma unroll
        for (int j = 0; j < 8; ++j) r[j] = (_Float16)p[j];
        return r;
    }
}

template <int PRE>
__global__ __launch_bounds__(512, 4)
void win_attn_mfma(const float* __restrict__ x,
                   const void* __restrict__ wqkv,
                   const void* __restrict__ wproj,
                   float* __restrict__ out)
{
    // LDS: 61.5 KB total -> 2 blocks/CU. All row strides are multiples of 16 B.
    __shared__ _Float16 x_t[NTOK][DIMC + 8];  // token-major x        33.0 KB
    __shared__ _Float16 q_t[NTOK][HD + 8];    // token-major q*scale   5.0 KB
    __shared__ _Float16 k_t[NTOK][HD + 8];    // token-major k         5.0 KB
    __shared__ _Float16 v_c[HD][NTOK + 8];    // CHANNEL-major v (=V^T) 4.5 KB
    __shared__ _Float16 p_t[NTOK][NTOK + 8];  // token-major P         9.0 KB
    __shared__ _Float16 ao_t[NTOK][HD + 8];   // token-major attn out  5.0 KB

    const int t  = threadIdx.x;
    const int ln = t & 15;                              // lane&15: tile col index
    const int lq = (t & 63) >> 4;                       // lane quadrant
    const int gu = __builtin_amdgcn_readfirstlane(t >> 6);  // wave id 0..7
    const int b  = blockIdx.z;
    const int y0 = blockIdx.y * WS;
    const int x0 = blockIdx.x * WS;

    // ---- stage x -> x_t (token-major fp16). 2048 chunks of 8 px, 4 per thread.
    {
        const float* xb = x + (long)b * DIMC * IMG + (long)y0 * HRES + x0;
        #pragma unroll
        for (int i = 0; i < 4; ++i) {
            int qq = i * 512 + t;
            int c = qq >> 3, py = qq & 7;
            const float* src = xb + (long)c * IMG + py * HRES;
            float4 f0 = *(const float4*)src;
            float4 f1 = *(const float4*)(src + 4);
            int n = py * 8;
            x_t[n + 0][c] = (_Float16)f0.x; x_t[n + 1][c] = (_Float16)f0.y;
            x_t[n + 2][c] = (_Float16)f0.z; x_t[n + 3][c] = (_Float16)f0.w;
            x_t[n + 4][c] = (_Float16)f1.x; x_t[n + 5][c] = (_Float16)f1.y;
            x_t[n + 6][c] = (_Float16)f1.z; x_t[n + 7][c] = (_Float16)f1.w;
        }
    }

    const f32x4 zero = {0.f, 0.f, 0.f, 0.f};
    f32x4 facc[8];                                      // proj accum: 8 tiles/wave
    #pragma unroll
    for (int i = 0; i < 8; ++i) facc[i] = zero;

    const float scale = 0.17677669529663687f;           // 1/sqrt(32), folded into q
    const int nt = gu & 3;                              // fixed n-tile per wave
    const int og = (gu >> 2) * 3;                       // first o-tile (3 per wave)
    const int nrow = nt * 16 + ln;

    // ---- QKV for head h: Y[96 x 64] = Wqkv_h[96 x 256] * X^T. 24 tiles / 8 waves.
    // nt fixed per wave => ONE ds_read_b128 x-fragment per K-step.
    auto qkv_head = [&](int h) {
        f32x4 a0c = zero, a1c = zero, a2c = zero;
        const int wr0 = (((og + 0) >> 1) * DIMC + h * HD + (((og + 0) & 1) << 4) + ln) * DIMC;
        const int wr1 = (((og + 1) >> 1) * DIMC + h * HD + (((og + 1) & 1) << 4) + ln) * DIMC;
        const int wr2 = (((og + 2) >> 1) * DIMC + h * HD + (((og + 2) & 1) << 4) + ln) * DIMC;
        #pragma unroll
        for (int c0 = 0; c0 < DIMC; c0 += 32) {
            const int co = c0 + 8 * lq;
            f16x8 bx = *(const f16x8*)&x_t[nrow][co];
            f16x8 a0 = ldw<PRE>(wqkv, wr0 + co);
            f16x8 a1 = ldw<PRE>(wqkv, wr1 + co);
            f16x8 a2 = ldw<PRE>(wqkv, wr2 + co);
            a0c = MFMA(a0, bx, a0c);
            a1c = MFMA(a1, bx, a1c);
            a2c = MFMA(a2, bx, a2c);
        }
        // store: D col=lane&15=n, row=4*lq+r.  q,k -> token-major; v -> channel-major.
        #pragma unroll
        for (int j = 0; j < 3; ++j) {
            f32x4 a = (j == 0) ? a0c : ((j == 1) ? a1c : a2c);
            const int ot = og + j;
            const int part = ot >> 1;
            const int dbase = ((ot & 1) << 4) + 4 * lq;
            #pragma unroll
            for (int r = 0; r < 4; ++r) {
                const float v = a[r];
                const int d = dbase + r;
                if (part == 0)      q_t[nrow][d] = (_Float16)(v * scale);
                else if (part == 1) k_t[nrow][d] = (_Float16)v;
                else                v_c[d][nrow]  = (_Float16)v;
            }
        }
    };

    // ---- attention for one head: waves 0..3, wave = one 16-wide q-tile.
    auto attn_head = [&]() {
        if (gu < 4) {
            const int qn = gu * 16 + ln;
            const int d8 = 8 * lq;
            // S^T tiles = mfma(K_rows, Q_rows): lane holds S[qn][kn], kn = 16*kt+4*lq+r
            f16x8 qf = *(const f16x8*)&q_t[qn][d8];
            f16x8 kf0 = *(const f16x8*)&k_t[ 0 + ln][d8];
            f16x8 kf1 = *(const f16x8*)&k_t[16 + ln][d8];
            f16x8 kf2 = *(const f16x8*)&k_t[32 + ln][d8];
            f16x8 kf3 = *(const f16x8*)&k_t[48 + ln][d8];
            f32x4 s0 = MFMA(kf0, qf, zero);
            f32x4 s1 = MFMA(kf1, qf, zero);
            f32x4 s2 = MFMA(kf2, qf, zero);
            f32x4 s3 = MFMA(kf3, qf, zero);
            // row softmax: 16 local values + butterfly over quadrant axis
            float mx = -1e30f;
            #pragma unroll
            for (int r = 0; r < 4; ++r)
                mx = fmaxf(mx, fmaxf(fmaxf(s0[r], s1[r]), fmaxf(s2[r], s3[r])));
            mx = fmaxf(mx, __shfl_xor(mx, 16));
            mx = fmaxf(mx, __shfl_xor(mx, 32));
            float sum = 0.f;
            #pragma unroll
            for (int r = 0; r < 4; ++r) {
                s0[r] = __expf(s0[r] - mx); sum += s0[r];
                s1[r] = __expf(s1[r] - mx); sum += s1[r];
                s2[r] = __expf(s2[r] - mx); sum += s2[r];
                s3[r] = __expf(s3[r] - mx); sum += s3[r];
            }
            sum += __shfl_xor(sum, 16);
            sum += __shfl_xor(sum, 32);
            const float inv = 1.f / sum;
            // pack 4 consecutive kn per reg group -> f16x4 stores, token-major P
            const int kb = 4 * lq;
            f16x4 pv;
            #pragma unroll
            for (int r = 0; r < 4; ++r) pv[r] = (_Float16)(s0[r] * inv);
            *(f16x4*)&p_t[qn][ 0 + kb] = pv;
            #pragma unroll
            for (int r = 0; r < 4; ++r) pv[r] = (_Float16)(s1[r] * inv);
            *(f16x4*)&p_t[qn][16 + kb] = pv;
            #pragma unroll
            for (int r = 0; r < 4; ++r) pv[r] = (_Float16)(s2[r] * inv);
            *(f16x4*)&p_t[qn][32 + kb] = pv;
            #pragma unroll
            for (int r = 0; r < 4; ++r) pv[r] = (_Float16)(s3[r] * inv);
            *(f16x4*)&p_t[qn][48 + kb] = pv;

            // PV: O^T[d][qn] = mfma(Vt_rows(d), P_rows(qn)) over m=64 (2 K-steps)
            f32x4 o0 = zero, o1 = zero;
            #pragma unroll
            for (int ks = 0; ks < 2; ++ks) {
                const int m0 = ks * 32 + 8 * lq;
                f16x8 pf = *(const f16x8*)&p_t[qn][m0];
                f16x8 v0 = *(const f16x8*)&v_c[ 0 + ln][m0];
                f16x8 v1 = *(const f16x8*)&v_c[16 + ln][m0];
                o0 = MFMA(v0, pf, o0);
                o1 = MFMA(v1, pf, o1);
            }
            // D col=qn, row=d (4 consecutive per reg) -> packed token-major ao
            const int db = 4 * lq;
            f16x4 av;
            #pragma unroll
            for (int r = 0; r < 4; ++r) av[r] = (_Float16)o0[r];
            *(f16x4*)&ao_t[qn][db] = av;
            #pragma unroll
            for (int r = 0; r < 4; ++r) av[r] = (_Float16)o1[r];
            *(f16x4*)&ao_t[qn][16 + db] = av;
        }
    };

    // ---- proj: OUT[256 x 64] += Wproj[:, h*32:+32] * AO_h. 64 tiles, 8/wave, K=32.
    auto proj_head = [&](int h) {
        const int cb = h * HD + 8 * lq;
        f16x8 a0 = ldw<PRE>(wproj, ((gu * 2 + 0) * 16 + ln) * DIMC + cb);
        f16x8 a1 = ldw<PRE>(wproj, ((gu * 2 + 1) * 16 + ln) * DIMC + cb);
        #pragma unroll
        for (int np = 0; np < 4; ++np) {
            f16x8 bv = *(const f16x8*)&ao_t[np * 16 + ln][8 * lq];
            facc[np]     = MFMA(a0, bv, facc[np]);
            facc[4 + np] = MFMA(a1, bv, facc[4 + np]);
        }
    };

    __syncthreads();
    qkv_head(0);
    __syncthreads();
    for (int h = 0; h < NH; ++h) {
        attn_head();                 // waves 0-3 (reads q/k/v/p, writes p/ao)
        __syncthreads();
        proj_head(h);                // all waves read ao(h)
        if (h < NH - 1) qkv_head(h + 1);  // overlapped: writes q/k/v for next head
        __syncthreads();
    }

    // ---- epilogue: OUT tiles D col=n, row=o. o strided by IMG (channel-major out).
    {
        float* ob = out + (long)b * DIMC * IMG + (long)y0 * HRES + x0;
        #pragma unroll
        for (int i = 0; i < 8; ++i) {
            const int ot = gu * 2 + (i >> 2);
            const int n  = (i & 3) * 16 + ln;
            const int py = n >> 3, pxx = n & 7;
            float* op = ob + (long)(ot * 16 + 4 * lq) * IMG + py * HRES + pxx;
            op[0 * IMG] = facc[i][0];
            op[1 * IMG] = facc[i][1];
            op[2 * IMG] = facc[i][2];
            op[3 * IMG] = facc[i][3];
        }
    }
}

extern "C" void kernel_launch(void* const* d_in, const int* in_sizes, int n_in,
                              void* d_out, int out_size, void* d_ws, size_t ws_size,
                              hipStream_t stream)
{
    const float* x      = (const float*)d_in[0];
    const float* w_qkv  = (const float*)d_in[1];
    const float* w_proj = (const float*)d_in[2];
    float* out          = (float*)d_out;

    dim3 grid(HRES / WS, HRES / WS, 4);
    dim3 block(512);

    const size_t need = (size_t)(768 * 256 + 256 * 256) * sizeof(_Float16);
    if (d_ws && ws_size >= need) {
        _Float16* wq = (_Float16*)d_ws;
        _Float16* wp = wq + 768 * 256;
        hipLaunchKernelGGL(cvt_weights, dim3(1024), dim3(256), 0, stream,
                           w_qkv, w_proj, wq, wp);
        hipLaunchKernelGGL((win_attn_mfma<1>), grid, block, 0, stream,
                           x, (const void*)wq, (const void*)wp, out);
    } else {
        hipLaunchKernelGGL((win_attn_mfma<0>), grid, block, 0, stream,
                           x, (const void*)w_qkv, (const void*)w_proj, out);
    }
}

// Round 2
// 1013.125 us; speedup vs baseline: 8.1040x; 1.2497x over previous
//
#include <hip/hip_runtime.h>

// WindowAttentionLite, wave-per-head MFMA design.
// x(4,256,256,256) fp32, w_qkv(768,256), w_proj(256,256). WINDOW=8 -> 64 tok,
// 8 heads, head_dim=32. One block per window, 8 waves, wave g owns head g.
// Q/K/V live in registers (V computed with swapped MFMA operands so PV needs
// no LDS transpose); only x and attn-out are staged in LDS. 2 barriers/block.

#define DIMC 256
#define NH   8
#define HD   32
#define WS   8
#define NTOK 64
#define HRES 256
#define IMG  (HRES * HRES)

#define XPITCH 272   // f16 per LDS row: 544 B = 136 dw == 8 (mod 32) -> balanced banks

typedef _Float16 f16x8 __attribute__((ext_vector_type(8)));
typedef _Float16 f16x4 __attribute__((ext_vector_type(4)));
typedef float    f32x4 __attribute__((ext_vector_type(4)));

#define MFMA(a, b, c) __builtin_amdgcn_mfma_f32_16x16x32_f16((a), (b), (c), 0, 0, 0)

// ---------- prologue: convert weights fp32 -> fp16 into workspace ----------
__global__ __launch_bounds__(256) void cvt_weights(const float* __restrict__ wqkv,
                                                   const float* __restrict__ wproj,
                                                   _Float16* __restrict__ wq,
                                                   _Float16* __restrict__ wp)
{
    int i = blockIdx.x * 256 + threadIdx.x;
    const int NQ = 768 * 256;
    const int NT = NQ + 256 * 256;
    if (i < NQ)      wq[i] = (_Float16)wqkv[i];
    else if (i < NT) wp[i - NQ] = (_Float16)wproj[i - NQ];
}

template <int PRE>
__device__ __forceinline__ f16x8 ldw(const void* w, int idx)
{
    if constexpr (PRE) {
        return *(const f16x8*)((const _Float16*)w + idx);
    } else {
        const float* p = (const float*)w + idx;
        f16x8 r;
        #pragma unroll
        for (int j = 0; j < 8; ++j) r[j] = (_Float16)p[j];
        return r;
    }
}

__device__ __forceinline__ int2 shfl2(int2 v, int s)
{
    v.x = __shfl(v.x, s);
    v.y = __shfl(v.y, s);
    return v;
}

__device__ __forceinline__ int2 pack4(f32x4 a)
{
    f16x4 h;
    h[0] = (_Float16)a[0]; h[1] = (_Float16)a[1];
    h[2] = (_Float16)a[2]; h[3] = (_Float16)a[3];
    return __builtin_bit_cast(int2, h);
}

__device__ __forceinline__ f16x8 cat8(int2 lo, int2 hi)
{
    int4 w = {lo.x, lo.y, hi.x, hi.y};
    return __builtin_bit_cast(f16x8, w);
}

// Universal quadrant redistribution: D-layout packs (col=lane&15, row=4*lq'+r,
// row-tile u in {pu0,pu1}) -> A/B fragment (lane&15 = col index, k = 8*lq+j).
// Shuffle both candidate packs, select by this lane's lq>>1 afterwards.
__device__ __forceinline__ f16x8 bfrag(int2 pu0, int2 pu1, int ln, int lq)
{
    const int slo = ln + 32 * (lq & 1);
    int2 l0 = shfl2(pu0, slo), h0 = shfl2(pu0, slo + 16);
    int2 l1 = shfl2(pu1, slo), h1 = shfl2(pu1, slo + 16);
    int2 lo = (lq & 2) ? l1 : l0;
    int2 hi = (lq & 2) ? h1 : h0;
    return cat8(lo, hi);
}

template <int PRE>
__global__ __launch_bounds__(512, 4)
void win_attn_mfma(const float* __restrict__ x,
                   const void* __restrict__ wqkv,
                   const void* __restrict__ wproj,
                   float* __restrict__ out)
{
    // LDS: 2 x 34,816 B = 69.6 KB -> 2 blocks/CU (needs VGPR <= 128).
    __shared__ _Float16 x_t[NTOK][XPITCH];   // token-major x (fp16)
    __shared__ _Float16 ao_t[NTOK][XPITCH];  // token-major attn-out, all heads

    const int t  = threadIdx.x;
    const int ln = t & 15;                  // tile col index
    const int lq = (t & 63) >> 4;           // lane quadrant
    const int gu = __builtin_amdgcn_readfirstlane(t >> 6);  // wave id = head id

    // Bijective XCD swizzle: dispatch-linear id -> contiguous window chunk per
    // XCD, so adjacent x-windows (sharing 64B HBM lines) hit the same L2.
    const int lin = blockIdx.x + (blockIdx.y << 5) + (blockIdx.z << 10);
    const int w   = ((lin & 7) << 9) | (lin >> 3);
    const int b   = w >> 10;
    const int y0  = ((w >> 5) & 31) * WS;
    const int x0  = (w & 31) * WS;

    const f32x4 zero = {0.f, 0.f, 0.f, 0.f};
    const float scale = 0.17677669529663687f;  // 1/sqrt(32), folded into Q pack

    // ---- stage x -> x_t: 8x8 in-register shfl transpose, b128 stores ----
    {
        const int py = t & 7;
        const int cg = (t & 63) >> 3;
        const float* xb = x + (long)b * DIMC * IMG + (long)(y0 + py) * HRES + x0;
        #pragma unroll
        for (int i = 0; i < 4; ++i) {
            const int cbase = i * 64 + gu * 8;
            const float* src = xb + (long)(cbase + cg) * IMG;
            float4 f0 = *(const float4*)src;
            float4 f1 = *(const float4*)(src + 4);
            float v[8] = {f0.x, f0.y, f0.z, f0.w, f1.x, f1.y, f1.z, f1.w};
            #pragma unroll
            for (int s = 1; s < 8; s <<= 1) {
                float nv[8];
                #pragma unroll
                for (int j = 0; j < 8; ++j) {
                    float ex = __shfl_xor(v[j ^ s], 8 * s);   // all lanes issue
                    nv[j] = ((j ^ cg) & s) ? ex : v[j];
                }
                #pragma unroll
                for (int j = 0; j < 8; ++j) v[j] = nv[j];
            }
            // lane now holds token 8*py+cg, channels cbase..cbase+7
            f16x8 hv;
            #pragma unroll
            for (int j = 0; j < 8; ++j) hv[j] = (_Float16)v[j];
            *(f16x8*)&x_t[8 * py + cg][cbase] = hv;
        }
    }
    __syncthreads();

    // ---- QKV for head gu, entirely per-wave. Two mt-passes (VGPR control).
    // Q,K: D = mfma(W rows, x tokens)  -> col=token, row=d
    // V:   D = mfma(x tokens, W rows)  -> col=d, row=token  (feeds PV directly)
    int2 Qp[2][4], Kp[2][4], Vp[4][2];
    #pragma unroll
    for (int mt = 0; mt < 2; ++mt) {
        f32x4 aq[4], ak[4], av[4];
        #pragma unroll
        for (int nt = 0; nt < 4; ++nt) { aq[nt] = zero; ak[nt] = zero; av[nt] = zero; }
        const int rq = (          gu * HD + 16 * mt + ln) * DIMC;
        const int rk = (DIMC    + gu * HD + 16 * mt + ln) * DIMC;
        const int rv = (2 * DIMC + gu * HD + 16 * mt + ln) * DIMC;
        #pragma unroll
        for (int ks = 0; ks < 8; ++ks) {
            const int co = 32 * ks + 8 * lq;
            f16x8 wqf = ldw<PRE>(wqkv, rq + co);
            f16x8 wkf = ldw<PRE>(wqkv, rk + co);
            f16x8 wvf = ldw<PRE>(wqkv, rv + co);
            #pragma unroll
            for (int nt = 0; nt < 4; ++nt) {
                f16x8 xf = *(const f16x8*)&x_t[16 * nt + ln][co];
                aq[nt] = MFMA(wqf, xf, aq[nt]);
                ak[nt] = MFMA(wkf, xf, ak[nt]);
                av[nt] = MFMA(xf, wvf, av[nt]);
            }
        }
        #pragma unroll
        for (int nt = 0; nt < 4; ++nt) {
            Qp[mt][nt] = pack4(aq[nt] * scale);
            Kp[mt][nt] = pack4(ak[nt]);
            Vp[nt][mt] = pack4(av[nt]);
        }
    }

    // ---- attention for head gu, no LDS, no barriers ----
    {
        f16x8 kf[4], qf[4];
        #pragma unroll
        for (int kt = 0; kt < 4; ++kt) kf[kt] = bfrag(Kp[0][kt], Kp[1][kt], ln, lq);
        #pragma unroll
        for (int qt = 0; qt < 4; ++qt) qf[qt] = bfrag(Qp[0][qt], Qp[1][qt], ln, lq);

        f32x4 s[4][4];   // S[ktok][qtok]: col=qtok(ln), row=ktok(4*lq+r), tile(kt,qt)
        #pragma unroll
        for (int kt = 0; kt < 4; ++kt)
            #pragma unroll
            for (int qt = 0; qt < 4; ++qt)
                s[kt][qt] = MFMA(kf[kt], qf[qt], zero);

        float inv[4];
        #pragma unroll
        for (int qt = 0; qt < 4; ++qt) {
            float m = -1e30f;
            #pragma unroll
            for (int kt = 0; kt < 4; ++kt)
                #pragma unroll
                for (int r = 0; r < 4; ++r) m = fmaxf(m, s[kt][qt][r]);
            m = fmaxf(m, __shfl_xor(m, 16));
            m = fmaxf(m, __shfl_xor(m, 32));
            float sum = 0.f;
            #pragma unroll
            for (int kt = 0; kt < 4; ++kt)
                #pragma unroll
                for (int r = 0; r < 4; ++r) {
                    float e = __expf(s[kt][qt][r] - m);
                    s[kt][qt][r] = e;
                    sum += e;
                }
            sum += __shfl_xor(sum, 16);
            sum += __shfl_xor(sum, 32);
            inv[qt] = 1.f / sum;
        }

        int2 Pp[4][4];
        #pragma unroll
        for (int kt = 0; kt < 4; ++kt)
            #pragma unroll
            for (int qt = 0; qt < 4; ++qt)
                Pp[kt][qt] = pack4(s[kt][qt] * inv[qt]);

        // PV: D[d][qtok] = mfma(V^T frag, P frag), contraction over 64 tokens
        f32x4 pv[2][4];
        #pragma unroll
        for (int dt = 0; dt < 2; ++dt)
            #pragma unroll
            for (int qt = 0; qt < 4; ++qt) pv[dt][qt] = zero;
        #pragma unroll
        for (int ks = 0; ks < 2; ++ks) {
            f16x8 vf[2], pf[4];
            #pragma unroll
            for (int dt = 0; dt < 2; ++dt)
                vf[dt] = bfrag(Vp[2 * ks][dt], Vp[2 * ks + 1][dt], ln, lq);
            #pragma unroll
            for (int qt = 0; qt < 4; ++qt)
                pf[qt] = bfrag(Pp[2 * ks][qt], Pp[2 * ks + 1][qt], ln, lq);
            #pragma unroll
            for (int dt = 0; dt < 2; ++dt)
                #pragma unroll
                for (int qt = 0; qt < 4; ++qt)
                    pv[dt][qt] = MFMA(vf[dt], pf[qt], pv[dt][qt]);
        }

        // write attn-out: ao[token][gu*32 + d], packed f16x4 (d consecutive)
        #pragma unroll
        for (int dt = 0; dt < 2; ++dt)
            #pragma unroll
            for (int qt = 0; qt < 4; ++qt) {
                f16x4 hv;
                #pragma unroll
                for (int r = 0; r < 4; ++r) hv[r] = (_Float16)pv[dt][qt][r];
                *(f16x4*)&ao_t[16 * qt + ln][gu * HD + 16 * dt + 4 * lq] = hv;
            }
    }
    __syncthreads();

    // ---- proj: OUT[256 x 64] = Wproj * AO, K = 256, per wave 2 o-tiles ----
    f32x4 fa[2][4];
    #pragma unroll
    for (int o = 0; o < 2; ++o)
        #pragma unroll
        for (int nt = 0; nt < 4; ++nt) fa[o][nt] = zero;
    {
        const int r0 = (16 * (2 * gu + 0) + ln) * DIMC;
        const int r1 = (16 * (2 * gu + 1) + ln) * DIMC;
        #pragma unroll
        for (int ks = 0; ks < 8; ++ks) {
            const int co = 32 * ks + 8 * lq;
            f16x8 w0 = ldw<PRE>(wproj, r0 + co);
            f16x8 w1 = ldw<PRE>(wproj, r1 + co);
            #pragma unroll
            for (int nt = 0; nt < 4; ++nt) {
                f16x8 af = *(const f16x8*)&ao_t[16 * nt + ln][co];
                fa[0][nt] = MFMA(w0, af, fa[0][nt]);
                fa[1][nt] = MFMA(w1, af, fa[1][nt]);
            }
        }
    }

    // ---- epilogue: D col=token(ln), row=och(4*lq+r); channel-major out ----
    {
        float* ob = out + (long)b * DIMC * IMG + (long)y0 * HRES + x0;
        #pragma unroll
        for (int o = 0; o < 2; ++o)
            #pragma unroll
            for (int nt = 0; nt < 4; ++nt) {
                const int och = 16 * (2 * gu + o) + 4 * lq;
                const int tok = 16 * nt + ln;
                float* op = ob + (long)och * IMG + (tok >> 3) * HRES + (tok & 7);
                #pragma unroll
                for (int r = 0; r < 4; ++r) op[(long)r * IMG] = fa[o][nt][r];
            }
    }
}

extern "C" void kernel_launch(void* const* d_in, const int* in_sizes, int n_in,
                              void* d_out, int out_size, void* d_ws, size_t ws_size,
                              hipStream_t stream)
{
    const float* x      = (const float*)d_in[0];
    const float* w_qkv  = (const float*)d_in[1];
    const float* w_proj = (const float*)d_in[2];
    float* out          = (float*)d_out;

    dim3 grid(HRES / WS, HRES / WS, 4);
    dim3 block(512);

    const size_t need = (size_t)(768 * 256 + 256 * 256) * sizeof(_Float16);
    if (d_ws && ws_size >= need) {
        _Float16* wq = (_Float16*)d_ws;
        _Float16* wp = wq + 768 * 256;
        hipLaunchKernelGGL(cvt_weights, dim3(1024), dim3(256), 0, stream,
                           w_qkv, w_proj, wq, wp);
        hipLaunchKernelGGL((win_attn_mfma<1>), grid, block, 0, stream,
                           x, (const void*)wq, (const void*)wp, out);
    } else {
        hipLaunchKernelGGL((win_attn_mfma<0>), grid, block, 0, stream,
                           x, (const void*)w_qkv, (const void*)w_proj, out);
    }
}